// Round 1
// baseline (351.750 us; speedup 1.0000x reference)
//
#include <hip/hip_runtime.h>
#include <cstddef>
#include <cstdint>

#define L_SEQ 1024
#define NCHUNK 32
#define CLEN 32

__device__ __forceinline__ float silu_f(float x) {
    return x / (1.f + __expf(-x));
}

// ---------------- Tiled f32 GEMM: C[M,N] = A[M,K] @ B[K,N] (+bias) ----------------
// 64x64 tile, BK=16, 256 threads, 4x4 register tile. M must be multiple of 64,
// N,K multiples of 4. ACT: 0 = none, 1 = softplus.
template<int ACT>
__global__ __launch_bounds__(256)
void gemm64(const float* __restrict__ A, int lda,
            const float* __restrict__ B, int ldb,
            const float* __restrict__ bias,
            float* __restrict__ C, int ldc,
            int M, int N, int K)
{
    __shared__ float As[16][68];   // [k][m], padded (68) -> 2-way max on writes
    __shared__ float Bs[16][64];   // [k][n]
    const int tid = threadIdx.x;
    const int tx = tid & 15, ty = tid >> 4;
    const int m0 = blockIdx.y * 64, n0 = blockIdx.x * 64;
    const int arow = tid >> 2, acol = (tid & 3) << 2;
    const int brow = tid >> 4, bcol = (tid & 15) << 2;
    float acc[4][4] = {};
    const float* Ap = A + (size_t)(m0 + arow) * lda + acol;
    const float* Bp = B + (size_t)brow * ldb + n0 + bcol;
    const bool bok = (n0 + bcol) < N;
    for (int k0 = 0; k0 < K; k0 += 16) {
        float4 av = make_float4(0.f, 0.f, 0.f, 0.f);
        float4 bv = make_float4(0.f, 0.f, 0.f, 0.f);
        if (k0 + acol < K) av = *(const float4*)(Ap + k0);
        if (bok && (k0 + brow) < K) bv = *(const float4*)(Bp + (size_t)k0 * ldb);
        As[acol + 0][arow] = av.x;
        As[acol + 1][arow] = av.y;
        As[acol + 2][arow] = av.z;
        As[acol + 3][arow] = av.w;
        *(float4*)&Bs[brow][bcol] = bv;
        __syncthreads();
        #pragma unroll
        for (int k = 0; k < 16; ++k) {
            float4 a4 = *(const float4*)&As[k][ty * 4];
            float4 b4 = *(const float4*)&Bs[k][tx * 4];
            float aa[4] = {a4.x, a4.y, a4.z, a4.w};
            float bb[4] = {b4.x, b4.y, b4.z, b4.w};
            #pragma unroll
            for (int i = 0; i < 4; ++i)
                #pragma unroll
                for (int j = 0; j < 4; ++j)
                    acc[i][j] = fmaf(aa[i], bb[j], acc[i][j]);
        }
        __syncthreads();
    }
    const int nn = n0 + tx * 4;
    if (nn >= N) return;
    float4 bf = make_float4(0.f, 0.f, 0.f, 0.f);
    if (bias) bf = *(const float4*)(bias + nn);
    #pragma unroll
    for (int i = 0; i < 4; ++i) {
        int m = m0 + ty * 4 + i;
        float o[4];
        o[0] = acc[i][0] + bf.x;
        o[1] = acc[i][1] + bf.y;
        o[2] = acc[i][2] + bf.z;
        o[3] = acc[i][3] + bf.w;
        if (ACT == 1) {
            #pragma unroll
            for (int j = 0; j < 4; ++j)
                o[j] = fmaxf(o[j], 0.f) + log1pf(expf(-fabsf(o[j])));
        }
        *(float4*)(C + (size_t)m * ldc + nn) = make_float4(o[0], o[1], o[2], o[3]);
    }
}

// ---------------- LayerNorm over 384, in place. One wave per row. ----------------
__global__ __launch_bounds__(256)
void ln_kernel(float* __restrict__ x, const float* __restrict__ g, const float* __restrict__ b)
{
    const int lane = threadIdx.x & 63;
    const int row = blockIdx.x * 4 + (threadIdx.x >> 6);
    float* p = x + (size_t)row * 384;
    float v[6];
    #pragma unroll
    for (int i = 0; i < 6; ++i) v[i] = p[i * 64 + lane];
    float s = v[0] + v[1] + v[2] + v[3] + v[4] + v[5];
    #pragma unroll
    for (int m = 32; m >= 1; m >>= 1) s += __shfl_xor(s, m);
    const float mu = s * (1.f / 384.f);
    float q = 0.f;
    #pragma unroll
    for (int i = 0; i < 6; ++i) { float dv = v[i] - mu; q = fmaf(dv, dv, q); }
    #pragma unroll
    for (int m = 32; m >= 1; m >>= 1) q += __shfl_xor(q, m);
    const float inv = 1.f / sqrtf(q * (1.f / 384.f) + 1e-5f);
    #pragma unroll
    for (int i = 0; i < 6; ++i) {
        int c = i * 64 + lane;
        p[c] = (v[i] - mu) * inv * g[c] + b[c];
    }
}

// ------- depthwise causal conv(4) + SiLU -> u ; then x_dbl = u @ W_x [768x56] -------
// 8 tokens per block (blocks never straddle a batch since 8 | 1024).
__global__ __launch_bounds__(256)
void conv_xdbl(const float* __restrict__ xr, const float* __restrict__ conv_w,
               const float* __restrict__ conv_b, const float* __restrict__ Wx,
               float* __restrict__ u, float* __restrict__ xdbl)
{
    __shared__ float us[8 * 772];   // stride 772 kills bank conflicts
    const int tid = threadIdx.x;
    const int tok0 = blockIdx.x * 8;
    const int t0 = tok0 & (L_SEQ - 1);
    #pragma unroll
    for (int dd = 0; dd < 3; ++dd) {
        int d = dd * 256 + tid;
        float w0 = conv_w[d * 4 + 0], w1 = conv_w[d * 4 + 1];
        float w2 = conv_w[d * 4 + 2], w3 = conv_w[d * 4 + 3];
        float cb = conv_b[d];
        #pragma unroll
        for (int tt = 0; tt < 8; ++tt) {
            int t = t0 + tt;
            const float* base = xr + (size_t)(tok0 + tt) * 1536 + d;
            float acc = cb;
            if (t >= 3) {
                acc = fmaf(base[-3 * 1536], w0, acc);
                acc = fmaf(base[-2 * 1536], w1, acc);
                acc = fmaf(base[-1 * 1536], w2, acc);
                acc = fmaf(base[0],         w3, acc);
            } else {
                if (t >= 3) acc = fmaf(base[-3 * 1536], w0, acc);
                if (t >= 2) acc = fmaf(base[-2 * 1536], w1, acc);
                if (t >= 1) acc = fmaf(base[-1 * 1536], w2, acc);
                acc = fmaf(base[0], w3, acc);
            }
            float sg = silu_f(acc);
            us[tt * 772 + d] = sg;
            u[(size_t)(tok0 + tt) * 768 + d] = sg;
        }
    }
    __syncthreads();
    for (int o = tid; o < 8 * 56; o += 256) {
        int tt = o / 56, c = o % 56;
        const float* ur = &us[tt * 772];
        float acc = 0.f;
        #pragma unroll 4
        for (int d4 = 0; d4 < 768; d4 += 4) {
            float4 uv = *(const float4*)&ur[d4];
            acc = fmaf(uv.x, Wx[(d4 + 0) * 56 + c], acc);
            acc = fmaf(uv.y, Wx[(d4 + 1) * 56 + c], acc);
            acc = fmaf(uv.z, Wx[(d4 + 2) * 56 + c], acc);
            acc = fmaf(uv.w, Wx[(d4 + 3) * 56 + c], acc);
        }
        xdbl[(size_t)(tok0 + tt) * 56 + c] = acc;
    }
}

// ---------------- chunked selective scan ----------------
// lane layout: n = tid&15 (state), dl = tid>>4 (16 d's per block)
__global__ __launch_bounds__(256)
void scan_a(const float* __restrict__ delta, const float* __restrict__ u,
            const float* __restrict__ xdbl, const float* __restrict__ A_log,
            float* __restrict__ Ac, float* __restrict__ Bc)
{
    const int tid = threadIdx.x;
    const int n = tid & 15, dl = tid >> 4;
    const int d = blockIdx.x * 16 + dl;
    const int c = blockIdx.y, b = blockIdx.z;
    const float Aval = -__expf(A_log[d * 16 + n]);
    float h = 0.f, dsum = 0.f;
    const int base = b * L_SEQ + c * CLEN;
    #pragma unroll 4
    for (int t = 0; t < CLEN; ++t) {
        const int row = base + t;
        float dt = delta[(size_t)row * 768 + d];
        float ut = u[(size_t)row * 768 + d];
        float Bv = xdbl[(size_t)row * 56 + 24 + n];
        float dA = __expf(dt * Aval);
        h = fmaf(dA, h, dt * ut * Bv);
        dsum += dt;
    }
    const size_t idx = (((size_t)(b * 768 + d)) * NCHUNK + c) * 16 + n;
    Ac[idx] = __expf(Aval * dsum);   // prod of exps == exp of sum
    Bc[idx] = h;
}

__global__ __launch_bounds__(256)
void scan_b(const float* __restrict__ Ac, const float* __restrict__ Bc,
            float* __restrict__ Hin)
{
    const size_t flat = (size_t)blockIdx.x * 256 + threadIdx.x;  // 0..49151
    const size_t bd = flat >> 4;
    const int n = (int)(flat & 15);
    const size_t base = bd * (NCHUNK * 16) + n;
    float h = 0.f;
    for (int c = 0; c < NCHUNK; ++c) {
        size_t i = base + (size_t)c * 16;
        Hin[i] = h;                     // exclusive: h at chunk start
        h = fmaf(Ac[i], h, Bc[i]);
    }
}

__global__ __launch_bounds__(256)
void scan_c(const float* __restrict__ delta, const float* __restrict__ u,
            const float* __restrict__ xdbl, const float* __restrict__ A_log,
            const float* __restrict__ Hin, const float* __restrict__ D_skip,
            const float* __restrict__ xr_res, float* __restrict__ yg)
{
    const int tid = threadIdx.x;
    const int n = tid & 15, dl = tid >> 4;
    const int d = blockIdx.x * 16 + dl;
    const int c = blockIdx.y, b = blockIdx.z;
    const float Aval = -__expf(A_log[d * 16 + n]);
    float h = Hin[(((size_t)(b * 768 + d)) * NCHUNK + c) * 16 + n];
    const float Ds = D_skip[d];
    const int base = b * L_SEQ + c * CLEN;
    #pragma unroll 4
    for (int t = 0; t < CLEN; ++t) {
        const int row = base + t;
        float dt = delta[(size_t)row * 768 + d];
        float ut = u[(size_t)row * 768 + d];
        float Bv = xdbl[(size_t)row * 56 + 24 + n];
        float Cv = xdbl[(size_t)row * 56 + 40 + n];
        float dA = __expf(dt * Aval);
        h = fmaf(dA, h, dt * ut * Bv);
        float yp = h * Cv;
        #pragma unroll
        for (int m = 8; m >= 1; m >>= 1) yp += __shfl_xor(yp, m);
        if (n == 0) {
            float res = xr_res[(size_t)row * 1536 + 768 + d];
            yg[(size_t)row * 1536 + d] = fmaf(ut, Ds, yp) * silu_f(res);
        }
    }
}

extern "C" void kernel_launch(void* const* d_in, const int* in_sizes, int n_in,
                              void* d_out, int out_size, void* d_ws, size_t ws_size,
                              hipStream_t stream)
{
    const float* ev     = (const float*)d_in[0];
    const float* rgb    = (const float*)d_in[1];
    const float* W_ev   = (const float*)d_in[2];
    const float* b_ev   = (const float*)d_in[3];
    const float* W_rgb  = (const float*)d_in[4];
    const float* b_rgb  = (const float*)d_in[5];
    const float* ln_g   = (const float*)d_in[6];
    const float* ln_b   = (const float*)d_in[7];
    const float* W_proj = (const float*)d_in[8];
    const float* b_proj = (const float*)d_in[9];
    const float* W_in   = (const float*)d_in[10];
    const float* conv_w = (const float*)d_in[11];
    const float* conv_b = (const float*)d_in[12];
    const float* W_x    = (const float*)d_in[13];
    const float* W_dt   = (const float*)d_in[14];
    const float* b_dt   = (const float*)d_in[15];
    const float* A_log  = (const float*)d_in[16];
    const float* D_skip = (const float*)d_in[17];
    const float* W_out  = (const float*)d_in[18];
    float* out = (float*)d_out;

    // workspace layout (floats)
    float* ws    = (float*)d_ws;
    float* xf    = ws;                       // 4096x384   (embed concat -> LN in place)
    float* xmm   = xf    + 1572864;          // 4096x384   (after proj)
    float* xr    = xmm   + 1572864;          // 4096x1536  (u_pre | res); yg written into cols 0..767
    float* u     = xr    + 6291456;          // 4096x768
    float* xdbl  = u     + 3145728;          // 4096x56    (dt | B | C)
    float* delta = xdbl  + 229376;           // 4096x768
    float* Hin   = delta + 3145728;          // 4x768x32x16
    float* Ac    = xf;                       // alias (xf dead after proj GEMM)
    float* Bc    = xmm;                      // alias (xmm dead after W_in GEMM)

    dim3 blk(256);

    // 1-2: embed GEMMs into concat buffer
    gemm64<0><<<dim3(3, 64), blk, 0, stream>>>(ev, 128, W_ev, 192, b_ev, xf, 384, 4096, 192, 128);
    gemm64<0><<<dim3(3, 64), blk, 0, stream>>>(rgb, 128, W_rgb, 192, b_rgb, xf + 192, 384, 4096, 192, 128);
    // 3: LayerNorm in place
    ln_kernel<<<1024, blk, 0, stream>>>(xf, ln_g, ln_b);
    // 4: proj
    gemm64<0><<<dim3(6, 64), blk, 0, stream>>>(xf, 384, W_proj, 384, b_proj, xmm, 384, 4096, 384, 384);
    // 5: W_in
    gemm64<0><<<dim3(24, 64), blk, 0, stream>>>(xmm, 384, W_in, 1536, nullptr, xr, 1536, 4096, 1536, 384);
    // 6: conv + silu -> u ; x_dbl = u @ W_x
    conv_xdbl<<<512, blk, 0, stream>>>(xr, conv_w, conv_b, W_x, u, xdbl);
    // 7: delta = softplus(dt @ W_dt + b_dt)   (dt = xdbl[:, :24], lda = 56)
    gemm64<1><<<dim3(12, 64), blk, 0, stream>>>(xdbl, 56, W_dt, 768, b_dt, delta, 768, 4096, 768, 24);
    // 8-10: chunked selective scan, gating fused into phase C
    scan_a<<<dim3(48, NCHUNK, 4), blk, 0, stream>>>(delta, u, xdbl, A_log, Ac, Bc);
    scan_b<<<192, blk, 0, stream>>>(Ac, Bc, Hin);
    scan_c<<<dim3(48, NCHUNK, 4), blk, 0, stream>>>(delta, u, xdbl, A_log, Hin, D_skip, xr, xr);
    // 11: out GEMM (reads gated y from xr cols 0..767 with lda=1536)
    gemm64<0><<<dim3(6, 64), blk, 0, stream>>>(xr, 1536, W_out, 384, nullptr, out, 384, 4096, 384, 768);
}

// Round 2
// 290.857 us; speedup vs baseline: 1.2094x; 1.2094x over previous
//
#include <hip/hip_runtime.h>
#include <cstddef>
#include <cstdint>

#define L_SEQ 1024
#define NCHUNK 64
#define CLEN 16

__device__ __forceinline__ float silu_f(float x) {
    return x / (1.f + __expf(-x));
}

__device__ __forceinline__ float exp2_fast(float x) {
#if __has_builtin(__builtin_amdgcn_exp2f)
    return __builtin_amdgcn_exp2f(x);
#else
    return exp2f(x);
#endif
}

// ---------------- Tiled f32 GEMM: C[M,N] = A[M,K] @ B[K,N] (+bias) ----------------
// 64x64 tile, BK=16, 256 threads, 4x4 register tile. M must be multiple of 64,
// N,K multiples of 4. ACT: 0 = none, 1 = softplus.
template<int ACT>
__global__ __launch_bounds__(256)
void gemm64(const float* __restrict__ A, int lda,
            const float* __restrict__ B, int ldb,
            const float* __restrict__ bias,
            float* __restrict__ C, int ldc,
            int M, int N, int K)
{
    __shared__ float As[16][68];   // [k][m], padded
    __shared__ float Bs[16][64];   // [k][n]
    const int tid = threadIdx.x;
    const int tx = tid & 15, ty = tid >> 4;
    const int m0 = blockIdx.y * 64, n0 = blockIdx.x * 64;
    const int arow = tid >> 2, acol = (tid & 3) << 2;
    const int brow = tid >> 4, bcol = (tid & 15) << 2;
    float acc[4][4] = {};
    const float* Ap = A + (size_t)(m0 + arow) * lda + acol;
    const float* Bp = B + (size_t)brow * ldb + n0 + bcol;
    const bool bok = (n0 + bcol) < N;
    for (int k0 = 0; k0 < K; k0 += 16) {
        float4 av = make_float4(0.f, 0.f, 0.f, 0.f);
        float4 bv = make_float4(0.f, 0.f, 0.f, 0.f);
        if (k0 + acol < K) av = *(const float4*)(Ap + k0);
        if (bok && (k0 + brow) < K) bv = *(const float4*)(Bp + (size_t)k0 * ldb);
        As[acol + 0][arow] = av.x;
        As[acol + 1][arow] = av.y;
        As[acol + 2][arow] = av.z;
        As[acol + 3][arow] = av.w;
        *(float4*)&Bs[brow][bcol] = bv;
        __syncthreads();
        #pragma unroll
        for (int k = 0; k < 16; ++k) {
            float4 a4 = *(const float4*)&As[k][ty * 4];
            float4 b4 = *(const float4*)&Bs[k][tx * 4];
            float aa[4] = {a4.x, a4.y, a4.z, a4.w};
            float bb[4] = {b4.x, b4.y, b4.z, b4.w};
            #pragma unroll
            for (int i = 0; i < 4; ++i)
                #pragma unroll
                for (int j = 0; j < 4; ++j)
                    acc[i][j] = fmaf(aa[i], bb[j], acc[i][j]);
        }
        __syncthreads();
    }
    const int nn = n0 + tx * 4;
    if (nn >= N) return;
    float4 bf = make_float4(0.f, 0.f, 0.f, 0.f);
    if (bias) bf = *(const float4*)(bias + nn);
    #pragma unroll
    for (int i = 0; i < 4; ++i) {
        int m = m0 + ty * 4 + i;
        float o[4];
        o[0] = acc[i][0] + bf.x;
        o[1] = acc[i][1] + bf.y;
        o[2] = acc[i][2] + bf.z;
        o[3] = acc[i][3] + bf.w;
        if (ACT == 1) {
            #pragma unroll
            for (int j = 0; j < 4; ++j)
                o[j] = fmaxf(o[j], 0.f) + log1pf(expf(-fabsf(o[j])));
        }
        *(float4*)(C + (size_t)m * ldc + nn) = make_float4(o[0], o[1], o[2], o[3]);
    }
}

// ---------------- LayerNorm over 384, in place. One wave per row. ----------------
__global__ __launch_bounds__(256)
void ln_kernel(float* __restrict__ x, const float* __restrict__ g, const float* __restrict__ b)
{
    const int lane = threadIdx.x & 63;
    const int row = blockIdx.x * 4 + (threadIdx.x >> 6);
    float* p = x + (size_t)row * 384;
    float v[6];
    #pragma unroll
    for (int i = 0; i < 6; ++i) v[i] = p[i * 64 + lane];
    float s = v[0] + v[1] + v[2] + v[3] + v[4] + v[5];
    #pragma unroll
    for (int m = 32; m >= 1; m >>= 1) s += __shfl_xor(s, m);
    const float mu = s * (1.f / 384.f);
    float q = 0.f;
    #pragma unroll
    for (int i = 0; i < 6; ++i) { float dv = v[i] - mu; q = fmaf(dv, dv, q); }
    #pragma unroll
    for (int m = 32; m >= 1; m >>= 1) q += __shfl_xor(q, m);
    const float inv = 1.f / sqrtf(q * (1.f / 384.f) + 1e-5f);
    #pragma unroll
    for (int i = 0; i < 6; ++i) {
        int c = i * 64 + lane;
        p[c] = (v[i] - mu) * inv * g[c] + b[c];
    }
}

// ------- depthwise causal conv(4) + SiLU -> u ; then x_dbl = u @ W_x [768x56] -------
__global__ __launch_bounds__(256)
void conv_xdbl(const float* __restrict__ xr, const float* __restrict__ conv_w,
               const float* __restrict__ conv_b, const float* __restrict__ Wx,
               float* __restrict__ u, float* __restrict__ xdbl)
{
    __shared__ float us[8 * 772];
    const int tid = threadIdx.x;
    const int tok0 = blockIdx.x * 8;
    const int t0 = tok0 & (L_SEQ - 1);
    #pragma unroll
    for (int dd = 0; dd < 3; ++dd) {
        int d = dd * 256 + tid;
        float w0 = conv_w[d * 4 + 0], w1 = conv_w[d * 4 + 1];
        float w2 = conv_w[d * 4 + 2], w3 = conv_w[d * 4 + 3];
        float cb = conv_b[d];
        #pragma unroll
        for (int tt = 0; tt < 8; ++tt) {
            int t = t0 + tt;
            const float* base = xr + (size_t)(tok0 + tt) * 1536 + d;
            float acc = cb;
            if (t >= 3) {
                acc = fmaf(base[-3 * 1536], w0, acc);
                acc = fmaf(base[-2 * 1536], w1, acc);
                acc = fmaf(base[-1 * 1536], w2, acc);
                acc = fmaf(base[0],         w3, acc);
            } else {
                if (t >= 2) acc = fmaf(base[-2 * 1536], w1, acc);
                if (t >= 1) acc = fmaf(base[-1 * 1536], w2, acc);
                acc = fmaf(base[0], w3, acc);
            }
            float sg = silu_f(acc);
            us[tt * 772 + d] = sg;
            u[(size_t)(tok0 + tt) * 768 + d] = sg;
        }
    }
    __syncthreads();
    for (int o = tid; o < 8 * 56; o += 256) {
        int tt = o / 56, c = o % 56;
        const float* ur = &us[tt * 772];
        float acc = 0.f;
        #pragma unroll 4
        for (int d4 = 0; d4 < 768; d4 += 4) {
            float4 uv = *(const float4*)&ur[d4];
            acc = fmaf(uv.x, Wx[(d4 + 0) * 56 + c], acc);
            acc = fmaf(uv.y, Wx[(d4 + 1) * 56 + c], acc);
            acc = fmaf(uv.z, Wx[(d4 + 2) * 56 + c], acc);
            acc = fmaf(uv.w, Wx[(d4 + 3) * 56 + c], acc);
        }
        xdbl[(size_t)(tok0 + tt) * 56 + c] = acc;
    }
}

// ---------------- chunked selective scan, reduction-free ----------------
// Thread owns one d and all 16 n-states in registers. Lanes = consecutive d
// (coalesced dt/u). B/C staged in LDS per chunk (broadcast reads).
__global__ __launch_bounds__(256)
void scan_a2(const float* __restrict__ delta, const float* __restrict__ u,
             const float* __restrict__ xdbl, const float* __restrict__ A_log,
             float* __restrict__ Ac, float* __restrict__ Bc)
{
    __shared__ float Bsh[CLEN][16];
    const int tid = threadIdx.x;
    const int d = blockIdx.x * 256 + tid;
    const int c = blockIdx.y, b = blockIdx.z;
    const int row0 = b * L_SEQ + c * CLEN;
    {
        int t = tid >> 4, n = tid & 15;
        Bsh[t][n] = xdbl[(size_t)(row0 + t) * 56 + 24 + n];
    }
    float AL2[16];
    {
        const float* ap = A_log + d * 16;
        #pragma unroll
        for (int n = 0; n < 16; ++n)
            AL2[n] = -__expf(ap[n]) * 1.44269504f;   // Aval * log2(e)
    }
    __syncthreads();
    float h[16];
    #pragma unroll
    for (int n = 0; n < 16; ++n) h[n] = 0.f;
    float dsum = 0.f;
    const float* dp = delta + (size_t)row0 * 768 + d;
    const float* up = u + (size_t)row0 * 768 + d;
    #pragma unroll 4
    for (int t = 0; t < CLEN; ++t) {
        float dt = dp[t * 768];
        float ut = up[t * 768];
        float du = dt * ut;
        dsum += dt;
        #pragma unroll
        for (int n = 0; n < 16; ++n) {
            float dA = exp2_fast(dt * AL2[n]);
            h[n] = fmaf(dA, h[n], du * Bsh[t][n]);
        }
    }
    float* acp = Ac + (((size_t)(b * 768 + d)) * NCHUNK + c) * 16;
    float* bcp = Bc + (((size_t)(b * 768 + d)) * NCHUNK + c) * 16;
    #pragma unroll
    for (int n = 0; n < 16; ++n) {
        acp[n] = exp2_fast(AL2[n] * dsum);  // prod of exps == exp of sum
        bcp[n] = h[n];
    }
}

// sequential chunk combine; Hin written IN PLACE over Bc (read-before-write per elem)
__global__ __launch_bounds__(256)
void scan_b2(const float* __restrict__ Ac, float* __restrict__ BcHin)
{
    const size_t flat = (size_t)blockIdx.x * 256 + threadIdx.x;  // 0..49151
    const size_t bd = flat >> 4;
    const int n = (int)(flat & 15);
    const size_t base = bd * (NCHUNK * 16) + n;
    float h = 0.f;
    for (int c = 0; c < NCHUNK; ++c) {
        size_t i = base + (size_t)c * 16;
        float a = Ac[i];
        float bb = BcHin[i];
        BcHin[i] = h;                    // exclusive prefix: h at chunk start
        h = fmaf(a, h, bb);
    }
}

__global__ __launch_bounds__(256)
void scan_c2(const float* __restrict__ delta, const float* __restrict__ u,
             const float* __restrict__ xdbl, const float* __restrict__ A_log,
             const float* __restrict__ Hin, const float* __restrict__ D_skip,
             float* __restrict__ xr)   // res in cols 768..1535; gated y -> cols 0..767
{
    __shared__ float Bsh[CLEN][16];
    __shared__ float Csh[CLEN][16];
    const int tid = threadIdx.x;
    const int d = blockIdx.x * 256 + tid;
    const int c = blockIdx.y, b = blockIdx.z;
    const int row0 = b * L_SEQ + c * CLEN;
    {
        int t = tid >> 4, n = tid & 15;
        const float* xp = xdbl + (size_t)(row0 + t) * 56;
        Bsh[t][n] = xp[24 + n];
        Csh[t][n] = xp[40 + n];
    }
    float AL2[16];
    {
        const float* ap = A_log + d * 16;
        #pragma unroll
        for (int n = 0; n < 16; ++n)
            AL2[n] = -__expf(ap[n]) * 1.44269504f;
    }
    float h[16];
    {
        const float* hp = Hin + (((size_t)(b * 768 + d)) * NCHUNK + c) * 16;
        #pragma unroll
        for (int n = 0; n < 16; ++n) h[n] = hp[n];
    }
    const float Ds = D_skip[d];
    __syncthreads();
    const float* dp = delta + (size_t)row0 * 768 + d;
    const float* up = u + (size_t)row0 * 768 + d;
    const float* rp = xr + (size_t)row0 * 1536 + 768 + d;
    float* yp = xr + (size_t)row0 * 1536 + d;
    #pragma unroll 4
    for (int t = 0; t < CLEN; ++t) {
        float dt = dp[t * 768];
        float ut = up[t * 768];
        float du = dt * ut;
        float y = 0.f;
        #pragma unroll
        for (int n = 0; n < 16; ++n) {
            float dA = exp2_fast(dt * AL2[n]);
            h[n] = fmaf(dA, h[n], du * Bsh[t][n]);
            y = fmaf(h[n], Csh[t][n], y);
        }
        float res = rp[t * 1536];
        yp[t * 1536] = fmaf(ut, Ds, y) * silu_f(res);
    }
}

extern "C" void kernel_launch(void* const* d_in, const int* in_sizes, int n_in,
                              void* d_out, int out_size, void* d_ws, size_t ws_size,
                              hipStream_t stream)
{
    const float* ev     = (const float*)d_in[0];
    const float* rgb    = (const float*)d_in[1];
    const float* W_ev   = (const float*)d_in[2];
    const float* b_ev   = (const float*)d_in[3];
    const float* W_rgb  = (const float*)d_in[4];
    const float* b_rgb  = (const float*)d_in[5];
    const float* ln_g   = (const float*)d_in[6];
    const float* ln_b   = (const float*)d_in[7];
    const float* W_proj = (const float*)d_in[8];
    const float* b_proj = (const float*)d_in[9];
    const float* W_in   = (const float*)d_in[10];
    const float* conv_w = (const float*)d_in[11];
    const float* conv_b = (const float*)d_in[12];
    const float* W_x    = (const float*)d_in[13];
    const float* W_dt   = (const float*)d_in[14];
    const float* b_dt   = (const float*)d_in[15];
    const float* A_log  = (const float*)d_in[16];
    const float* D_skip = (const float*)d_in[17];
    const float* W_out  = (const float*)d_in[18];
    float* out = (float*)d_out;

    // workspace layout (floats)
    float* ws    = (float*)d_ws;
    float* xf    = ws;                       // 4096x384   (embed concat -> LN in place)
    float* xmm   = xf    + 1572864;          // 4096x384   (after proj)
    float* xr    = xmm   + 1572864;          // 4096x1536  (u_pre | res); yg -> cols 0..767
    float* u     = xr    + 6291456;          // 4096x768
    float* xdbl  = u     + 3145728;          // 4096x56    (dt | B | C)
    float* delta = xdbl  + 229376;           // 4096x768
    float* BcHin = delta + 3145728;          // 4x768x64x16 (Bc, then Hin in place)
    float* Ac    = xf;                       // alias: xf+xmm = 3,145,728 floats, exact fit

    dim3 blk(256);

    gemm64<0><<<dim3(3, 64), blk, 0, stream>>>(ev, 128, W_ev, 192, b_ev, xf, 384, 4096, 192, 128);
    gemm64<0><<<dim3(3, 64), blk, 0, stream>>>(rgb, 128, W_rgb, 192, b_rgb, xf + 192, 384, 4096, 192, 128);
    ln_kernel<<<1024, blk, 0, stream>>>(xf, ln_g, ln_b);
    gemm64<0><<<dim3(6, 64), blk, 0, stream>>>(xf, 384, W_proj, 384, b_proj, xmm, 384, 4096, 384, 384);
    gemm64<0><<<dim3(24, 64), blk, 0, stream>>>(xmm, 384, W_in, 1536, nullptr, xr, 1536, 4096, 1536, 384);
    conv_xdbl<<<512, blk, 0, stream>>>(xr, conv_w, conv_b, W_x, u, xdbl);
    gemm64<1><<<dim3(12, 64), blk, 0, stream>>>(xdbl, 56, W_dt, 768, b_dt, delta, 768, 4096, 768, 24);
    scan_a2<<<dim3(3, NCHUNK, 4), blk, 0, stream>>>(delta, u, xdbl, A_log, Ac, BcHin);
    scan_b2<<<192, blk, 0, stream>>>(Ac, BcHin);
    scan_c2<<<dim3(3, NCHUNK, 4), blk, 0, stream>>>(delta, u, xdbl, A_log, BcHin, D_skip, xr);
    gemm64<0><<<dim3(6, 64), blk, 0, stream>>>(xr, 1536, W_out, 384, nullptr, out, 384, 4096, 384, 768);
}

// Round 3
// 228.257 us; speedup vs baseline: 1.5410x; 1.2743x over previous
//
#include <hip/hip_runtime.h>
#include <cstddef>
#include <cstdint>

#define L_SEQ 1024
#define NCHUNK 64
#define CLEN 16

typedef __bf16 bf16x8 __attribute__((ext_vector_type(8)));
typedef float f32x4 __attribute__((ext_vector_type(4)));

__device__ __forceinline__ float silu_f(float x) {
    return x / (1.f + __expf(-x));
}

__device__ __forceinline__ float exp2_fast(float x) {
    return exp2f(x);
}

__device__ __forceinline__ unsigned short f2bf(float x) {
    union { float f; unsigned int u; } v; v.f = x;
    unsigned int r = (v.u + 0x7fffu + ((v.u >> 16) & 1u)) >> 16;
    return (unsigned short)r;
}
__device__ __forceinline__ float bf2f(unsigned short h) {
    union { float f; unsigned int u; } v; v.u = ((unsigned int)h) << 16;
    return v.f;
}

// ---------------- f32 GEMM (embeds, dt). WHILO=1 writes bf16 hi/lo planes ----------------
template<int ACT, int WHILO>
__global__ __launch_bounds__(256)
void gemm64(const float* __restrict__ A, int lda,
            const float* __restrict__ B, int ldb,
            const float* __restrict__ bias,
            float* __restrict__ Cf,
            unsigned short* __restrict__ Chi, unsigned short* __restrict__ Clo,
            int ldc, int M, int N, int K)
{
    __shared__ float As[16][68];
    __shared__ float Bs[16][64];
    const int tid = threadIdx.x;
    const int tx = tid & 15, ty = tid >> 4;
    const int m0 = blockIdx.y * 64, n0 = blockIdx.x * 64;
    const int arow = tid >> 2, acol = (tid & 3) << 2;
    const int brow = tid >> 4, bcol = (tid & 15) << 2;
    float acc[4][4] = {};
    const float* Ap = A + (size_t)(m0 + arow) * lda + acol;
    const float* Bp = B + (size_t)brow * ldb + n0 + bcol;
    const bool bok = (n0 + bcol) < N;
    for (int k0 = 0; k0 < K; k0 += 16) {
        float4 av = make_float4(0.f, 0.f, 0.f, 0.f);
        float4 bv = make_float4(0.f, 0.f, 0.f, 0.f);
        if (k0 + acol < K) av = *(const float4*)(Ap + k0);
        if (bok && (k0 + brow) < K) bv = *(const float4*)(Bp + (size_t)k0 * ldb);
        As[acol + 0][arow] = av.x;
        As[acol + 1][arow] = av.y;
        As[acol + 2][arow] = av.z;
        As[acol + 3][arow] = av.w;
        *(float4*)&Bs[brow][bcol] = bv;
        __syncthreads();
        #pragma unroll
        for (int k = 0; k < 16; ++k) {
            float4 a4 = *(const float4*)&As[k][ty * 4];
            float4 b4 = *(const float4*)&Bs[k][tx * 4];
            float aa[4] = {a4.x, a4.y, a4.z, a4.w};
            float bb[4] = {b4.x, b4.y, b4.z, b4.w};
            #pragma unroll
            for (int i = 0; i < 4; ++i)
                #pragma unroll
                for (int j = 0; j < 4; ++j)
                    acc[i][j] = fmaf(aa[i], bb[j], acc[i][j]);
        }
        __syncthreads();
    }
    const int nn = n0 + tx * 4;
    if (nn >= N) return;
    float4 bf = make_float4(0.f, 0.f, 0.f, 0.f);
    if (bias) bf = *(const float4*)(bias + nn);
    #pragma unroll
    for (int i = 0; i < 4; ++i) {
        int m = m0 + ty * 4 + i;
        float o[4];
        o[0] = acc[i][0] + bf.x;
        o[1] = acc[i][1] + bf.y;
        o[2] = acc[i][2] + bf.z;
        o[3] = acc[i][3] + bf.w;
        if (ACT == 1) {
            #pragma unroll
            for (int j = 0; j < 4; ++j)
                o[j] = fmaxf(o[j], 0.f) + log1pf(expf(-fabsf(o[j])));
        }
        if (WHILO) {
            #pragma unroll
            for (int j = 0; j < 4; ++j) {
                unsigned short h = f2bf(o[j]);
                Chi[(size_t)m * ldc + nn + j] = h;
                Clo[(size_t)m * ldc + nn + j] = f2bf(o[j] - bf2f(h));
            }
        } else {
            *(float4*)(Cf + (size_t)m * ldc + nn) = make_float4(o[0], o[1], o[2], o[3]);
        }
    }
}

// ---------------- bf16x3 MFMA GEMM: 128x128 tile, BK=32, 4 waves ----------------
// A from hi/lo planes [M][K] (or packed (hi<<16|lo) uints), B pre-transposed hi/lo [N][K].
template<bool APK, bool WHILO>
__global__ __launch_bounds__(256)
void gemm_bf3(const unsigned short* __restrict__ Ahi,
              const unsigned short* __restrict__ Alo,
              const unsigned int* __restrict__ Apk, int lda,
              const unsigned short* __restrict__ Bthi,
              const unsigned short* __restrict__ Btlo,
              const float* __restrict__ bias,
              float* __restrict__ Cf,
              unsigned short* __restrict__ Chi, unsigned short* __restrict__ Clo,
              int ldc, int K)
{
    __shared__ unsigned short As[2][128][40];
    __shared__ unsigned short Bs[2][128][40];
    const int tid = threadIdx.x;
    const int lane = tid & 63;
    const int wave = tid >> 6;
    const int wm = wave >> 1, wn = wave & 1;
    const int m0 = blockIdx.y * 128, n0 = blockIdx.x * 128;
    const int srow = tid >> 1, sko = (tid & 1) * 16;

    f32x4 acc[4][4];
    #pragma unroll
    for (int i = 0; i < 4; ++i)
        #pragma unroll
        for (int j = 0; j < 4; ++j) {
            f32x4 z = {0.f, 0.f, 0.f, 0.f};
            acc[i][j] = z;
        }

    const size_t aoff = (size_t)(m0 + srow) * lda + sko;
    const size_t boff = (size_t)(n0 + srow) * K + sko;

    for (int k0 = 0; k0 < K; k0 += 32) {
        if constexpr (!APK) {
            uint4 h0 = *(const uint4*)(Ahi + aoff + k0);
            uint4 h1 = *(const uint4*)(Ahi + aoff + k0 + 8);
            uint4 l0 = *(const uint4*)(Alo + aoff + k0);
            uint4 l1 = *(const uint4*)(Alo + aoff + k0 + 8);
            *(uint4*)&As[0][srow][sko]     = h0;
            *(uint4*)&As[0][srow][sko + 8] = h1;
            *(uint4*)&As[1][srow][sko]     = l0;
            *(uint4*)&As[1][srow][sko + 8] = l1;
        } else {
            const unsigned int* ap = Apk + aoff + k0;
            uint4 p0 = *(const uint4*)(ap);
            uint4 p1 = *(const uint4*)(ap + 4);
            uint4 p2 = *(const uint4*)(ap + 8);
            uint4 p3 = *(const uint4*)(ap + 12);
            uint4 h0, h1, l0, l1;
            h0.x = (p0.x >> 16) | (p0.y & 0xffff0000u);
            h0.y = (p0.z >> 16) | (p0.w & 0xffff0000u);
            h0.z = (p1.x >> 16) | (p1.y & 0xffff0000u);
            h0.w = (p1.z >> 16) | (p1.w & 0xffff0000u);
            h1.x = (p2.x >> 16) | (p2.y & 0xffff0000u);
            h1.y = (p2.z >> 16) | (p2.w & 0xffff0000u);
            h1.z = (p3.x >> 16) | (p3.y & 0xffff0000u);
            h1.w = (p3.z >> 16) | (p3.w & 0xffff0000u);
            l0.x = (p0.x & 0xffffu) | (p0.y << 16);
            l0.y = (p0.z & 0xffffu) | (p0.w << 16);
            l0.z = (p1.x & 0xffffu) | (p1.y << 16);
            l0.w = (p1.z & 0xffffu) | (p1.w << 16);
            l1.x = (p2.x & 0xffffu) | (p2.y << 16);
            l1.y = (p2.z & 0xffffu) | (p2.w << 16);
            l1.z = (p3.x & 0xffffu) | (p3.y << 16);
            l1.w = (p3.z & 0xffffu) | (p3.w << 16);
            *(uint4*)&As[0][srow][sko]     = h0;
            *(uint4*)&As[0][srow][sko + 8] = h1;
            *(uint4*)&As[1][srow][sko]     = l0;
            *(uint4*)&As[1][srow][sko + 8] = l1;
        }
        {
            uint4 bh0 = *(const uint4*)(Bthi + boff + k0);
            uint4 bh1 = *(const uint4*)(Bthi + boff + k0 + 8);
            uint4 bl0 = *(const uint4*)(Btlo + boff + k0);
            uint4 bl1 = *(const uint4*)(Btlo + boff + k0 + 8);
            *(uint4*)&Bs[0][srow][sko]     = bh0;
            *(uint4*)&Bs[0][srow][sko + 8] = bh1;
            *(uint4*)&Bs[1][srow][sko]     = bl0;
            *(uint4*)&Bs[1][srow][sko + 8] = bl1;
        }
        __syncthreads();
        const int fr = lane & 15, kq = lane >> 4;
        bf16x8 aH[4], aL[4];
        #pragma unroll
        for (int i = 0; i < 4; ++i) {
            aH[i] = *(const bf16x8*)&As[0][wm * 64 + i * 16 + fr][kq * 8];
            aL[i] = *(const bf16x8*)&As[1][wm * 64 + i * 16 + fr][kq * 8];
        }
        #pragma unroll
        for (int j = 0; j < 4; ++j) {
            bf16x8 bH = *(const bf16x8*)&Bs[0][wn * 64 + j * 16 + fr][kq * 8];
            bf16x8 bL = *(const bf16x8*)&Bs[1][wn * 64 + j * 16 + fr][kq * 8];
            #pragma unroll
            for (int i = 0; i < 4; ++i)
                acc[i][j] = __builtin_amdgcn_mfma_f32_16x16x32_bf16(aH[i], bH, acc[i][j], 0, 0, 0);
            #pragma unroll
            for (int i = 0; i < 4; ++i)
                acc[i][j] = __builtin_amdgcn_mfma_f32_16x16x32_bf16(aL[i], bH, acc[i][j], 0, 0, 0);
            #pragma unroll
            for (int i = 0; i < 4; ++i)
                acc[i][j] = __builtin_amdgcn_mfma_f32_16x16x32_bf16(aH[i], bL, acc[i][j], 0, 0, 0);
        }
        __syncthreads();
    }
    const int col = lane & 15, rq = lane >> 4;
    #pragma unroll
    for (int j = 0; j < 4; ++j) {
        int nn = n0 + wn * 64 + j * 16 + col;
        float bv = bias ? bias[nn] : 0.f;
        #pragma unroll
        for (int i = 0; i < 4; ++i) {
            int mb = m0 + wm * 64 + i * 16 + rq * 4;
            #pragma unroll
            for (int r = 0; r < 4; ++r) {
                float o = acc[i][j][r] + bv;
                if (WHILO) {
                    unsigned short h = f2bf(o);
                    Chi[(size_t)(mb + r) * ldc + nn] = h;
                    Clo[(size_t)(mb + r) * ldc + nn] = f2bf(o - bf2f(h));
                } else {
                    Cf[(size_t)(mb + r) * ldc + nn] = o;
                }
            }
        }
    }
}

// ---------------- transpose + hi/lo split of weights: W[K][N] -> Wt[N][K] ----------------
__global__ __launch_bounds__(256)
void wcvt(const float* __restrict__ W, unsigned short* __restrict__ Thi,
          unsigned short* __restrict__ Tlo, int K, int N)
{
    __shared__ float t[32][33];
    const int tid = threadIdx.x;
    const int n0 = blockIdx.x * 32, k0 = blockIdx.y * 32;
    const int r = tid >> 3, c4 = (tid & 7) * 4;
    float4 v = *(const float4*)(W + (size_t)(k0 + r) * N + n0 + c4);
    t[r][c4 + 0] = v.x; t[r][c4 + 1] = v.y; t[r][c4 + 2] = v.z; t[r][c4 + 3] = v.w;
    __syncthreads();
    unsigned short hs[4], ls[4];
    #pragma unroll
    for (int j = 0; j < 4; ++j) {
        float x = t[c4 + j][r];
        hs[j] = f2bf(x);
        ls[j] = f2bf(x - bf2f(hs[j]));
    }
    size_t o = (size_t)(n0 + r) * K + k0 + c4;
    uint2 hv, lv;
    hv.x = (unsigned)hs[0] | ((unsigned)hs[1] << 16);
    hv.y = (unsigned)hs[2] | ((unsigned)hs[3] << 16);
    lv.x = (unsigned)ls[0] | ((unsigned)ls[1] << 16);
    lv.y = (unsigned)ls[2] | ((unsigned)ls[3] << 16);
    *(uint2*)(Thi + o) = hv;
    *(uint2*)(Tlo + o) = lv;
}

// ---------------- LayerNorm over 384, on hi/lo planes, in place ----------------
__global__ __launch_bounds__(256)
void ln2(unsigned short* __restrict__ hi, unsigned short* __restrict__ lo,
         const float* __restrict__ g, const float* __restrict__ b)
{
    const int lane = threadIdx.x & 63;
    const int row = blockIdx.x * 4 + (threadIdx.x >> 6);
    unsigned short* ph = hi + (size_t)row * 384;
    unsigned short* pl = lo + (size_t)row * 384;
    float v[6];
    #pragma unroll
    for (int i = 0; i < 6; ++i) {
        int c = i * 64 + lane;
        v[i] = bf2f(ph[c]) + bf2f(pl[c]);
    }
    float s = v[0] + v[1] + v[2] + v[3] + v[4] + v[5];
    #pragma unroll
    for (int m = 32; m >= 1; m >>= 1) s += __shfl_xor(s, m);
    const float mu = s * (1.f / 384.f);
    float q = 0.f;
    #pragma unroll
    for (int i = 0; i < 6; ++i) { float dv = v[i] - mu; q = fmaf(dv, dv, q); }
    #pragma unroll
    for (int m = 32; m >= 1; m >>= 1) q += __shfl_xor(q, m);
    const float inv = 1.f / sqrtf(q * (1.f / 384.f) + 1e-5f);
    #pragma unroll
    for (int i = 0; i < 6; ++i) {
        int c = i * 64 + lane;
        float o = (v[i] - mu) * inv * g[c] + b[c];
        unsigned short h = f2bf(o);
        ph[c] = h;
        pl[c] = f2bf(o - bf2f(h));
    }
}

// ------- depthwise causal conv(4) + SiLU -> u ; then x_dbl = u @ W_x [768x56] -------
__global__ __launch_bounds__(256)
void conv_xdbl(const float* __restrict__ xr, const float* __restrict__ conv_w,
               const float* __restrict__ conv_b, const float* __restrict__ Wx,
               float* __restrict__ u, float* __restrict__ xdbl)
{
    __shared__ float us[8 * 772];
    const int tid = threadIdx.x;
    const int tok0 = blockIdx.x * 8;
    const int t0 = tok0 & (L_SEQ - 1);
    #pragma unroll
    for (int dd = 0; dd < 3; ++dd) {
        int d = dd * 256 + tid;
        float w0 = conv_w[d * 4 + 0], w1 = conv_w[d * 4 + 1];
        float w2 = conv_w[d * 4 + 2], w3 = conv_w[d * 4 + 3];
        float cb = conv_b[d];
        #pragma unroll
        for (int tt = 0; tt < 8; ++tt) {
            int t = t0 + tt;
            const float* base = xr + (size_t)(tok0 + tt) * 1536 + d;
            float acc = cb;
            if (t >= 3) {
                acc = fmaf(base[-3 * 1536], w0, acc);
                acc = fmaf(base[-2 * 1536], w1, acc);
                acc = fmaf(base[-1 * 1536], w2, acc);
                acc = fmaf(base[0],         w3, acc);
            } else {
                if (t >= 2) acc = fmaf(base[-2 * 1536], w1, acc);
                if (t >= 1) acc = fmaf(base[-1 * 1536], w2, acc);
                acc = fmaf(base[0], w3, acc);
            }
            float sg = silu_f(acc);
            us[tt * 772 + d] = sg;
            u[(size_t)(tok0 + tt) * 768 + d] = sg;
        }
    }
    __syncthreads();
    for (int o = tid; o < 8 * 56; o += 256) {
        int tt = o / 56, c = o % 56;
        const float* ur = &us[tt * 772];
        float acc = 0.f;
        #pragma unroll 4
        for (int d4 = 0; d4 < 768; d4 += 4) {
            float4 uv = *(const float4*)&ur[d4];
            acc = fmaf(uv.x, Wx[(d4 + 0) * 56 + c], acc);
            acc = fmaf(uv.y, Wx[(d4 + 1) * 56 + c], acc);
            acc = fmaf(uv.z, Wx[(d4 + 2) * 56 + c], acc);
            acc = fmaf(uv.w, Wx[(d4 + 3) * 56 + c], acc);
        }
        xdbl[(size_t)(tok0 + tt) * 56 + c] = acc;
    }
}

// ---------------- chunked selective scan ----------------
__global__ __launch_bounds__(256)
void scan_a2(const float* __restrict__ delta, const float* __restrict__ u,
             const float* __restrict__ xdbl, const float* __restrict__ A_log,
             float* __restrict__ dsum_out, float* __restrict__ Bc)
{
    __shared__ float Bsh[CLEN][16];
    const int tid = threadIdx.x;
    const int d = blockIdx.x * 256 + tid;
    const int c = blockIdx.y, b = blockIdx.z;
    const int row0 = b * L_SEQ + c * CLEN;
    {
        int t = tid >> 4, n = tid & 15;
        Bsh[t][n] = xdbl[(size_t)(row0 + t) * 56 + 24 + n];
    }
    float AL2[16];
    {
        const float* ap = A_log + d * 16;
        #pragma unroll
        for (int n = 0; n < 16; ++n)
            AL2[n] = -__expf(ap[n]) * 1.44269504f;
    }
    __syncthreads();
    float h[16];
    #pragma unroll
    for (int n = 0; n < 16; ++n) h[n] = 0.f;
    float dsum = 0.f;
    const float* dp = delta + (size_t)row0 * 768 + d;
    const float* up = u + (size_t)row0 * 768 + d;
    #pragma unroll 4
    for (int t = 0; t < CLEN; ++t) {
        float dt = dp[t * 768];
        float ut = up[t * 768];
        float du = dt * ut;
        dsum += dt;
        #pragma unroll
        for (int n = 0; n < 16; ++n) {
            float dA = exp2_fast(dt * AL2[n]);
            h[n] = fmaf(dA, h[n], du * Bsh[t][n]);
        }
    }
    dsum_out[(size_t)(b * 768 + d) * NCHUNK + c] = dsum;
    float* bcp = Bc + (((size_t)(b * 768 + d)) * NCHUNK + c) * 16;
    #pragma unroll
    for (int n = 0; n < 16; ++n) bcp[n] = h[n];
}

__global__ __launch_bounds__(256)
void scan_b2(const float* __restrict__ dsum, const float* __restrict__ A_log,
             float* __restrict__ BcHin)
{
    const size_t flat = (size_t)blockIdx.x * 256 + threadIdx.x;  // 0..49151
    const size_t bd = flat >> 4;
    const int n = (int)(flat & 15);
    const int d = (int)(bd % 768);
    const float AL2 = -__expf(A_log[d * 16 + n]) * 1.44269504f;
    const float* dsp = dsum + bd * NCHUNK;
    const size_t base = bd * (NCHUNK * 16) + n;
    float h = 0.f;
    for (int c = 0; c < NCHUNK; ++c) {
        size_t i = base + (size_t)c * 16;
        float a = exp2_fast(AL2 * dsp[c]);
        float bb = BcHin[i];
        BcHin[i] = h;
        h = fmaf(a, h, bb);
    }
}

__global__ __launch_bounds__(256)
void scan_c2(float* __restrict__ delta, const float* __restrict__ u,
             const float* __restrict__ xdbl, const float* __restrict__ A_log,
             const float* __restrict__ Hin, const float* __restrict__ D_skip,
             const float* __restrict__ xr)   // res in cols 768..1535; y packed over delta
{
    __shared__ float Bsh[CLEN][16];
    __shared__ float Csh[CLEN][16];
    const int tid = threadIdx.x;
    const int d = blockIdx.x * 256 + tid;
    const int c = blockIdx.y, b = blockIdx.z;
    const int row0 = b * L_SEQ + c * CLEN;
    {
        int t = tid >> 4, n = tid & 15;
        const float* xp = xdbl + (size_t)(row0 + t) * 56;
        Bsh[t][n] = xp[24 + n];
        Csh[t][n] = xp[40 + n];
    }
    float AL2[16];
    {
        const float* ap = A_log + d * 16;
        #pragma unroll
        for (int n = 0; n < 16; ++n)
            AL2[n] = -__expf(ap[n]) * 1.44269504f;
    }
    float h[16];
    {
        const float* hp = Hin + (((size_t)(b * 768 + d)) * NCHUNK + c) * 16;
        #pragma unroll
        for (int n = 0; n < 16; ++n) h[n] = hp[n];
    }
    const float Ds = D_skip[d];
    __syncthreads();
    float* dp = delta + (size_t)row0 * 768 + d;
    const float* up = u + (size_t)row0 * 768 + d;
    const float* rp = xr + (size_t)row0 * 1536 + 768 + d;
    #pragma unroll 4
    for (int t = 0; t < CLEN; ++t) {
        float dt = dp[t * 768];
        float ut = up[t * 768];
        float du = dt * ut;
        float y = 0.f;
        #pragma unroll
        for (int n = 0; n < 16; ++n) {
            float dA = exp2_fast(dt * AL2[n]);
            h[n] = fmaf(dA, h[n], du * Bsh[t][n]);
            y = fmaf(h[n], Csh[t][n], y);
        }
        float res = rp[t * 1536];
        float gy = fmaf(ut, Ds, y) * silu_f(res);
        unsigned short h16 = f2bf(gy);
        unsigned short l16 = f2bf(gy - bf2f(h16));
        unsigned int pk = ((unsigned int)h16 << 16) | (unsigned int)l16;
        dp[t * 768] = __builtin_bit_cast(float, pk);   // y packed in place over delta
    }
}

extern "C" void kernel_launch(void* const* d_in, const int* in_sizes, int n_in,
                              void* d_out, int out_size, void* d_ws, size_t ws_size,
                              hipStream_t stream)
{
    const float* ev     = (const float*)d_in[0];
    const float* rgb    = (const float*)d_in[1];
    const float* W_ev   = (const float*)d_in[2];
    const float* b_ev   = (const float*)d_in[3];
    const float* W_rgb  = (const float*)d_in[4];
    const float* b_rgb  = (const float*)d_in[5];
    const float* ln_g   = (const float*)d_in[6];
    const float* ln_b   = (const float*)d_in[7];
    const float* W_proj = (const float*)d_in[8];
    const float* b_proj = (const float*)d_in[9];
    const float* W_in   = (const float*)d_in[10];
    const float* conv_w = (const float*)d_in[11];
    const float* conv_b = (const float*)d_in[12];
    const float* W_x    = (const float*)d_in[13];
    const float* W_dt   = (const float*)d_in[14];
    const float* b_dt   = (const float*)d_in[15];
    const float* A_log  = (const float*)d_in[16];
    const float* D_skip = (const float*)d_in[17];
    const float* W_out  = (const float*)d_in[18];
    float* out = (float*)d_out;

    // workspace layout (float units); high-water 17,825,792 floats = 71.3 MB
    float* ws = (float*)d_ws;
    unsigned short* xfh  = (unsigned short*)ws;                    // 4096x384 hi
    unsigned short* xfl  = xfh + 1572864;                          // 4096x384 lo
    float* dsum          = ws;                                     // alias (xf planes dead after proj)
    unsigned short* xmmh = (unsigned short*)(ws + 1572864);        // 4096x384 hi
    unsigned short* xmml = xmmh + 1572864;                         // lo
    float* u     = ws + 1572864;                                   // alias over xmm planes, 3,145,728 fl
    float* xr    = ws + 4718592;                                   // 4096x1536
    float* xdbl  = ws + 11010048;                                  // 4096x56
    float* delta = ws + 11239424;                                  // 4096x768 (y packed in place)
    float* BcHin = ws + 14385152;                                  // 4x768x64x16
    unsigned short* wtp_hi = (unsigned short*)BcHin;               // alias head (dead before scan_a2)
    unsigned short* wtp_lo = wtp_hi + 147456;
    unsigned short* wti_hi = wtp_lo + 147456;
    unsigned short* wti_lo = wti_hi + 589824;
    unsigned short* wto_hi = (unsigned short*)(ws + 17530880);     // persists to end
    unsigned short* wto_lo = wto_hi + 294912;

    dim3 blk(256);

    // weight transpose + hi/lo split
    wcvt<<<dim3(12, 12), blk, 0, stream>>>(W_proj, wtp_hi, wtp_lo, 384, 384);
    wcvt<<<dim3(48, 12), blk, 0, stream>>>(W_in,   wti_hi, wti_lo, 384, 1536);
    wcvt<<<dim3(12, 24), blk, 0, stream>>>(W_out,  wto_hi, wto_lo, 768, 384);

    // embeds (f32 GEMM, hi/lo epilogue into concat planes)
    gemm64<0, 1><<<dim3(3, 64), blk, 0, stream>>>(ev, 128, W_ev, 192, b_ev,
                                                  nullptr, xfh, xfl, 384, 4096, 192, 128);
    gemm64<0, 1><<<dim3(3, 64), blk, 0, stream>>>(rgb, 128, W_rgb, 192, b_rgb,
                                                  nullptr, xfh + 192, xfl + 192, 384, 4096, 192, 128);
    ln2<<<1024, blk, 0, stream>>>(xfh, xfl, ln_g, ln_b);

    // proj (bf16x3 MFMA) -> xmm planes
    gemm_bf3<false, true><<<dim3(3, 32), blk, 0, stream>>>(
        xfh, xfl, nullptr, 384, wtp_hi, wtp_lo, b_proj, nullptr, xmmh, xmml, 384, 384);
    // W_in (bf16x3 MFMA) -> xr f32
    gemm_bf3<false, false><<<dim3(12, 32), blk, 0, stream>>>(
        xmmh, xmml, nullptr, 384, wti_hi, wti_lo, nullptr, xr, nullptr, nullptr, 1536, 384);

    conv_xdbl<<<512, blk, 0, stream>>>(xr, conv_w, conv_b, W_x, u, xdbl);
    gemm64<1, 0><<<dim3(12, 64), blk, 0, stream>>>(xdbl, 56, W_dt, 768, b_dt,
                                                   delta, nullptr, nullptr, 768, 4096, 768, 24);

    scan_a2<<<dim3(3, NCHUNK, 4), blk, 0, stream>>>(delta, u, xdbl, A_log, dsum, BcHin);
    scan_b2<<<192, blk, 0, stream>>>(dsum, A_log, BcHin);
    scan_c2<<<dim3(3, NCHUNK, 4), blk, 0, stream>>>(delta, u, xdbl, A_log, BcHin, D_skip, xr);

    // out GEMM (bf16x3 MFMA, packed-A from delta zone) -> d_out
    gemm_bf3<true, false><<<dim3(3, 32), blk, 0, stream>>>(
        nullptr, nullptr, (const unsigned int*)delta, 768, wto_hi, wto_lo, nullptr,
        out, nullptr, nullptr, 384, 768);
}